// Round 3
// baseline (202.677 us; speedup 1.0000x reference)
//
#include <hip/hip_runtime.h>

// LocalEnergyOpt R3: R1 structure (LDS coords + params, direct strided conn
// reads) but sliced S=8 ways per system -> grid 2048, ~20 waves/CU resident.
// R1/R2 were latency-bound at 1 block/CU (Occupancy 20%, VALUBusy 6/19%).
// Partials -> d_ws, deterministic reduce kernel -> out (no atomics/memset).

#define BS 256
#define NSLICE 8

constexpr int MAXLEN  = 10000;
constexpr int N_ATOMS = 2000;
constexpr int NBT = 50, NAT = 100, NTT = 200;
constexpr float EPS = 1e-8f;

__global__ __launch_bounds__(BS) void energy_slice_kernel(
    const float* __restrict__ features,   // [B, 10000, 9]
    const int*   __restrict__ lengths,    // [B, 9]
    const float* __restrict__ opt_pars,   // [350, 3]
    const float* __restrict__ bond_type,  // [50]
    const float* __restrict__ angle_type, // [100]
    const float* __restrict__ tor_type,   // [200]
    float*       __restrict__ ws)         // [B * NSLICE] slice partials
{
    __shared__ float sc[3 * N_ATOMS];   // 24 KB coords
    __shared__ float sbp[3 * NBT];
    __shared__ float sap[3 * NAT];
    __shared__ float stp[3 * NTT];
    __shared__ float sw[BS / 64];

    const int blk = blockIdx.x;
    const int b   = blk >> 3;           // system
    const int s   = blk & (NSLICE - 1); // slice
    const int tid = threadIdx.x;
    const float* __restrict__ fb = features + (size_t)b * MAXLEN * 9;

    // ---- stage resolved param tables (tiny, L2-hot) ----
    for (int i = tid; i < NBT; i += BS) {
        int idx = (int)bond_type[i];
        sbp[3*i+0] = opt_pars[3*idx+0];
        sbp[3*i+1] = opt_pars[3*idx+1];
        sbp[3*i+2] = opt_pars[3*idx+2];
    }
    for (int i = tid; i < NAT; i += BS) {
        int idx = (int)angle_type[i];
        sap[3*i+0] = opt_pars[3*idx+0];
        sap[3*i+1] = opt_pars[3*idx+1];
        sap[3*i+2] = opt_pars[3*idx+2];
    }
    for (int i = tid; i < NTT; i += BS) {
        int idx = (int)tor_type[i];
        stp[3*i+0] = opt_pars[3*idx+0];
        stp[3*i+1] = opt_pars[3*idx+1];
        stp[3*i+2] = opt_pars[3*idx+2];
    }

    // ---- stage coords: fb[i*9+5], i in [0,6000) (L2/L3-served re-reads) ----
    #pragma unroll 4
    for (int i = tid; i < 3 * N_ATOMS; i += BS)
        sc[i] = fb[i * 9 + 5];
    __syncthreads();

    float acc = 0.0f;

    // ---- bonds slice: E = k * (r - r0)^2 ----
    {
        const int nb = lengths[b * 9 + 6] / 3;
        const int t0 = (nb * s) / NSLICE, t1 = (nb * (s + 1)) / NSLICE;
        const float* __restrict__ c6 = fb + 6;
        for (int t = t0 + tid; t < t1; t += BS) {
            const int base = 27 * t;
            int i  = (int)c6[base];
            int j  = (int)c6[base + 9];
            int ty = (int)c6[base + 18];
            float dx = sc[3*i+0] - sc[3*j+0];
            float dy = sc[3*i+1] - sc[3*j+1];
            float dz = sc[3*i+2] - sc[3*j+2];
            float r  = sqrtf(dx*dx + dy*dy + dz*dz + EPS);
            float k  = sbp[3*ty+0];
            float d  = r - sbp[3*ty+1];
            acc += k * d * d;
        }
    }

    // ---- angles slice: E = k * (theta - theta0)^2 ----
    {
        const int na = lengths[b * 9 + 7] / 4;
        const int t0 = (na * s) / NSLICE, t1 = (na * (s + 1)) / NSLICE;
        const float* __restrict__ c7 = fb + 7;
        for (int t = t0 + tid; t < t1; t += BS) {
            const int base = 36 * t;
            int i  = (int)c7[base];
            int j  = (int)c7[base + 9];
            int k_ = (int)c7[base + 18];
            int ty = (int)c7[base + 27];
            float jx = sc[3*j+0], jy = sc[3*j+1], jz = sc[3*j+2];
            float ux = sc[3*i+0] - jx, uy = sc[3*i+1] - jy, uz = sc[3*i+2] - jz;
            float vx = sc[3*k_+0] - jx, vy = sc[3*k_+1] - jy, vz = sc[3*k_+2] - jz;
            float uv = ux*vx + uy*vy + uz*vz;
            float uu = ux*ux + uy*uy + uz*uz;
            float vv = vx*vx + vy*vy + vz*vz;
            float c  = uv * rsqrtf((uu + EPS) * (vv + EPS));
            c = fminf(fmaxf(c, -1.0f + 1e-6f), 1.0f - 1e-6f);
            float theta = acosf(c);
            float k  = sap[3*ty+0];
            float d  = theta - sap[3*ty+1];
            acc += k * d * d;
        }
    }

    // ---- torsions slice: E = k * (1 + cos(n*phi - phi0)) ----
    {
        const int nt = lengths[b * 9 + 8] / 5;
        const int t0 = (nt * s) / NSLICE, t1 = (nt * (s + 1)) / NSLICE;
        const float* __restrict__ c8 = fb + 8;
        for (int t = t0 + tid; t < t1; t += BS) {
            const int base = 45 * t;
            int i  = (int)c8[base];
            int j  = (int)c8[base + 9];
            int k_ = (int)c8[base + 18];
            int l  = (int)c8[base + 27];
            int ty = (int)c8[base + 36];
            float ix = sc[3*i+0],  iy = sc[3*i+1],  iz = sc[3*i+2];
            float jx = sc[3*j+0],  jy = sc[3*j+1],  jz = sc[3*j+2];
            float kx = sc[3*k_+0], ky = sc[3*k_+1], kz = sc[3*k_+2];
            float lx = sc[3*l+0],  ly = sc[3*l+1],  lz = sc[3*l+2];
            float b1x = jx - ix, b1y = jy - iy, b1z = jz - iz;
            float b2x = kx - jx, b2y = ky - jy, b2z = kz - jz;
            float b3x = lx - kx, b3y = ly - ky, b3z = lz - kz;
            float n1x = b1y*b2z - b1z*b2y;
            float n1y = b1z*b2x - b1x*b2z;
            float n1z = b1x*b2y - b1y*b2x;
            float n2x = b2y*b3z - b2z*b3y;
            float n2y = b2z*b3x - b2x*b3z;
            float n2z = b2x*b3y - b2y*b3x;
            float inv = rsqrtf(b2x*b2x + b2y*b2y + b2z*b2z + EPS);
            float hx = b2x * inv, hy = b2y * inv, hz = b2z * inv;
            float m1x = n1y*hz - n1z*hy;
            float m1y = n1z*hx - n1x*hz;
            float m1z = n1x*hy - n1y*hx;
            float sy = m1x*n2x + m1y*n2y + m1z*n2z;
            float sx = n1x*n2x + n1y*n2y + n1z*n2z;
            float phi = atan2f(sy, sx);
            float k  = stp[3*ty+0];
            float p0 = stp[3*ty+1];
            float n  = stp[3*ty+2];
            acc += k * (1.0f + cosf(n * phi - p0));
        }
    }

    // ---- block reduce -> ws[blk] ----
    for (int off = 32; off > 0; off >>= 1)
        acc += __shfl_down(acc, off, 64);
    const int wave = tid >> 6, lane = tid & 63;
    if (lane == 0) sw[wave] = acc;
    __syncthreads();
    if (tid == 0) {
        float v = 0.0f;
        #pragma unroll
        for (int w = 0; w < BS / 64; ++w) v += sw[w];
        ws[blk] = v;
    }
}

__global__ __launch_bounds__(256) void reduce_kernel(
    const float* __restrict__ ws, float* __restrict__ out, int B)
{
    int b = blockIdx.x * 256 + threadIdx.x;
    if (b < B) {
        float v = 0.0f;
        #pragma unroll
        for (int i = 0; i < NSLICE; ++i) v += ws[b * NSLICE + i];
        out[b] = v;
    }
}

extern "C" void kernel_launch(void* const* d_in, const int* in_sizes, int n_in,
                              void* d_out, int out_size, void* d_ws, size_t ws_size,
                              hipStream_t stream) {
    const float* features   = (const float*)d_in[0];
    const int*   lengths    = (const int*)  d_in[1];
    const float* opt_pars   = (const float*)d_in[2];
    const float* bond_type  = (const float*)d_in[3];
    const float* angle_type = (const float*)d_in[4];
    const float* tor_type   = (const float*)d_in[5];
    float* out = (float*)d_out;
    float* ws  = (float*)d_ws;

    const int B = out_size;  // 256
    energy_slice_kernel<<<B * NSLICE, BS, 0, stream>>>(
        features, lengths, opt_pars, bond_type, angle_type, tor_type, ws);
    reduce_kernel<<<(B + 255) / 256, 256, 0, stream>>>(ws, out, B);
}

// Round 4
// 166.297 us; speedup vs baseline: 1.2188x; 1.2188x over previous
//
#include <hip/hip_runtime.h>

// LocalEnergyOpt R4: two-phase.
//  A) compact_kernel: one fully-coalesced float4 stream over features
//     [256,10000,9], demux cols 5-8 -> compact SoA in d_ws (coords f32,
//     connectivity u16). Grid-stride, no LDS, no sync -> full occupancy.
//  B) energy_slice_kernel: 2048 blocks (system x 8 slices) read compact
//     records (lane stride 6-10 B -> ~6-10 lines/wave vs 64 before) and
//     gather compact coords (chain locality -> near-coalesced, L1/L2-hot).
//  C) reduce partials -> out. No atomics, no memsets.
// R1-R3 evidence: stride-9 scalar gathers = 64 txn/wave (latency-bound,
// 55-95 us); features are L3-resident after harness restore (R2 FETCH 45MB).

#define BS 256
#define NSLICE 8

constexpr int BATCH   = 256;
constexpr int MAXLEN  = 10000;
constexpr int NBT = 50, NAT = 100, NTT = 200;
constexpr float EPS = 1e-8f;

// d_ws layout (bytes); total ~18.44 MB
constexpr size_t OFF_CC   = 0;                                  // [B][6000] f32 coords
constexpr size_t OFF_BC   = OFF_CC + (size_t)BATCH * 6000 * 4;  // [B][6000] u16 bonds
constexpr size_t OFF_AC   = OFF_BC + (size_t)BATCH * 6000 * 2;  // [B][8000] u16 angles
constexpr size_t OFF_TC   = OFF_AC + (size_t)BATCH * 8000 * 2;  // [B][10000] u16 torsions
constexpr size_t OFF_PART = OFF_TC + (size_t)BATCH * 10000 * 2; // [B*NSLICE] f32 partials

__global__ __launch_bounds__(256) void compact_kernel(
    const float* __restrict__ features,
    float* __restrict__ cc, unsigned short* __restrict__ bc,
    unsigned short* __restrict__ ac, unsigned short* __restrict__ tc)
{
    const unsigned NV = (unsigned)BATCH * 22500u;   // float4s total (5.76M)
    const float4* __restrict__ fv = (const float4*)features;
    const unsigned stride = gridDim.x * 256u;
    for (unsigned q = blockIdx.x * 256u + threadIdx.x; q < NV; q += stride) {
        float4 v = fv[q];
        unsigned b = q / 22500u;
        unsigned g = (q - b * 22500u) * 4u;         // float index within system
        float vals[4] = {v.x, v.y, v.z, v.w};
        #pragma unroll
        for (int e = 0; e < 4; ++e) {
            unsigned gg  = g + (unsigned)e;
            unsigned i   = gg / 9u;                  // row
            unsigned col = gg - 9u * i;
            float    val = vals[e];
            if (col == 5u)      { if (i < 6000u) cc[b * 6000u  + i] = val; }
            else if (col == 6u) { if (i < 5997u) bc[b * 6000u  + i] = (unsigned short)(int)val; }
            else if (col == 7u) { if (i < 7992u) ac[b * 8000u  + i] = (unsigned short)(int)val; }
            else if (col == 8u) { if (i < 9985u) tc[b * 10000u + i] = (unsigned short)(int)val; }
        }
    }
}

__global__ __launch_bounds__(BS) void energy_slice_kernel(
    const float* __restrict__ cc,          // compact coords [B][6000]
    const unsigned short* __restrict__ bc, // [B][6000]
    const unsigned short* __restrict__ ac, // [B][8000]
    const unsigned short* __restrict__ tc, // [B][10000]
    const int*   __restrict__ lengths,
    const float* __restrict__ opt_pars,
    const float* __restrict__ bond_type,
    const float* __restrict__ angle_type,
    const float* __restrict__ tor_type,
    float*       __restrict__ part)        // [B*NSLICE]
{
    __shared__ float sbp[3 * NBT];
    __shared__ float sap[3 * NAT];
    __shared__ float stp[3 * NTT];
    __shared__ float sw[BS / 64];

    const int blk = blockIdx.x;
    const int b   = blk >> 3;
    const int s   = blk & (NSLICE - 1);
    const int tid = threadIdx.x;

    for (int i = tid; i < NBT; i += BS) {
        int idx = (int)bond_type[i];
        sbp[3*i+0] = opt_pars[3*idx+0];
        sbp[3*i+1] = opt_pars[3*idx+1];
        sbp[3*i+2] = opt_pars[3*idx+2];
    }
    for (int i = tid; i < NAT; i += BS) {
        int idx = (int)angle_type[i];
        sap[3*i+0] = opt_pars[3*idx+0];
        sap[3*i+1] = opt_pars[3*idx+1];
        sap[3*i+2] = opt_pars[3*idx+2];
    }
    for (int i = tid; i < NTT; i += BS) {
        int idx = (int)tor_type[i];
        stp[3*i+0] = opt_pars[3*idx+0];
        stp[3*i+1] = opt_pars[3*idx+1];
        stp[3*i+2] = opt_pars[3*idx+2];
    }
    __syncthreads();

    const float*          c = cc + (size_t)b * 6000;
    const unsigned short* B_ = bc + (size_t)b * 6000;
    const unsigned short* A_ = ac + (size_t)b * 8000;
    const unsigned short* T_ = tc + (size_t)b * 10000;

    float acc = 0.0f;

    // ---- bonds: E = k * (r - r0)^2 ----
    {
        const int nb = lengths[b * 9 + 6] / 3;
        const int t0 = (nb * s) / NSLICE, t1 = (nb * (s + 1)) / NSLICE;
        for (int t = t0 + tid; t < t1; t += BS) {
            int i  = B_[3*t+0];
            int j  = B_[3*t+1];
            int ty = B_[3*t+2];
            float dx = c[3*i+0] - c[3*j+0];
            float dy = c[3*i+1] - c[3*j+1];
            float dz = c[3*i+2] - c[3*j+2];
            float r  = sqrtf(dx*dx + dy*dy + dz*dz + EPS);
            float k  = sbp[3*ty+0];
            float d  = r - sbp[3*ty+1];
            acc += k * d * d;
        }
    }

    // ---- angles: E = k * (theta - theta0)^2 ----
    {
        const int na = lengths[b * 9 + 7] / 4;
        const int t0 = (na * s) / NSLICE, t1 = (na * (s + 1)) / NSLICE;
        for (int t = t0 + tid; t < t1; t += BS) {
            int i  = A_[4*t+0];
            int j  = A_[4*t+1];
            int k_ = A_[4*t+2];
            int ty = A_[4*t+3];
            float jx = c[3*j+0], jy = c[3*j+1], jz = c[3*j+2];
            float ux = c[3*i+0] - jx, uy = c[3*i+1] - jy, uz = c[3*i+2] - jz;
            float vx = c[3*k_+0] - jx, vy = c[3*k_+1] - jy, vz = c[3*k_+2] - jz;
            float uv = ux*vx + uy*vy + uz*vz;
            float uu = ux*ux + uy*uy + uz*uz;
            float vv = vx*vx + vy*vy + vz*vz;
            float cth = uv * rsqrtf((uu + EPS) * (vv + EPS));
            cth = fminf(fmaxf(cth, -1.0f + 1e-6f), 1.0f - 1e-6f);
            float theta = acosf(cth);
            float k  = sap[3*ty+0];
            float d  = theta - sap[3*ty+1];
            acc += k * d * d;
        }
    }

    // ---- torsions: E = k * (1 + cos(n*phi - phi0)) ----
    {
        const int nt = lengths[b * 9 + 8] / 5;
        const int t0 = (nt * s) / NSLICE, t1 = (nt * (s + 1)) / NSLICE;
        for (int t = t0 + tid; t < t1; t += BS) {
            int i  = T_[5*t+0];
            int j  = T_[5*t+1];
            int k_ = T_[5*t+2];
            int l  = T_[5*t+3];
            int ty = T_[5*t+4];
            float ix = c[3*i+0],  iy = c[3*i+1],  iz = c[3*i+2];
            float jx = c[3*j+0],  jy = c[3*j+1],  jz = c[3*j+2];
            float kx = c[3*k_+0], ky = c[3*k_+1], kz = c[3*k_+2];
            float lx = c[3*l+0],  ly = c[3*l+1],  lz = c[3*l+2];
            float b1x = jx - ix, b1y = jy - iy, b1z = jz - iz;
            float b2x = kx - jx, b2y = ky - jy, b2z = kz - jz;
            float b3x = lx - kx, b3y = ly - ky, b3z = lz - kz;
            float n1x = b1y*b2z - b1z*b2y;
            float n1y = b1z*b2x - b1x*b2z;
            float n1z = b1x*b2y - b1y*b2x;
            float n2x = b2y*b3z - b2z*b3y;
            float n2y = b2z*b3x - b2x*b3z;
            float n2z = b2x*b3y - b2y*b3x;
            float inv = rsqrtf(b2x*b2x + b2y*b2y + b2z*b2z + EPS);
            float hx = b2x * inv, hy = b2y * inv, hz = b2z * inv;
            float m1x = n1y*hz - n1z*hy;
            float m1y = n1z*hx - n1x*hz;
            float m1z = n1x*hy - n1y*hx;
            float sy = m1x*n2x + m1y*n2y + m1z*n2z;
            float sx = n1x*n2x + n1y*n2y + n1z*n2z;
            float phi = atan2f(sy, sx);
            float k  = stp[3*ty+0];
            float p0 = stp[3*ty+1];
            float n  = stp[3*ty+2];
            acc += k * (1.0f + cosf(n * phi - p0));
        }
    }

    for (int off = 32; off > 0; off >>= 1)
        acc += __shfl_down(acc, off, 64);
    const int wave = tid >> 6, lane = tid & 63;
    if (lane == 0) sw[wave] = acc;
    __syncthreads();
    if (tid == 0) {
        float v = 0.0f;
        #pragma unroll
        for (int w = 0; w < BS / 64; ++w) v += sw[w];
        part[blk] = v;
    }
}

__global__ __launch_bounds__(256) void reduce_kernel(
    const float* __restrict__ part, float* __restrict__ out, int B)
{
    int b = blockIdx.x * 256 + threadIdx.x;
    if (b < B) {
        float v = 0.0f;
        #pragma unroll
        for (int i = 0; i < NSLICE; ++i) v += part[b * NSLICE + i];
        out[b] = v;
    }
}

extern "C" void kernel_launch(void* const* d_in, const int* in_sizes, int n_in,
                              void* d_out, int out_size, void* d_ws, size_t ws_size,
                              hipStream_t stream) {
    const float* features   = (const float*)d_in[0];
    const int*   lengths    = (const int*)  d_in[1];
    const float* opt_pars   = (const float*)d_in[2];
    const float* bond_type  = (const float*)d_in[3];
    const float* angle_type = (const float*)d_in[4];
    const float* tor_type   = (const float*)d_in[5];
    float* out = (float*)d_out;
    char*  ws  = (char*)d_ws;

    float*          cc   = (float*)(ws + OFF_CC);
    unsigned short* bc   = (unsigned short*)(ws + OFF_BC);
    unsigned short* ac   = (unsigned short*)(ws + OFF_AC);
    unsigned short* tc   = (unsigned short*)(ws + OFF_TC);
    float*          part = (float*)(ws + OFF_PART);

    const int B = out_size;  // 256

    compact_kernel<<<4096, 256, 0, stream>>>(features, cc, bc, ac, tc);
    energy_slice_kernel<<<B * NSLICE, BS, 0, stream>>>(
        cc, bc, ac, tc, lengths, opt_pars, bond_type, angle_type, tor_type, part);
    reduce_kernel<<<(B + 255) / 256, 256, 0, stream>>>(part, out, B);
}

// Round 5
// 153.442 us; speedup vs baseline: 1.3209x; 1.0838x over previous
//
#include <hip/hip_runtime.h>

// LocalEnergyOpt R5: two kernels.
//  A) compact_kernel: one thread per feature ROW. Key structural insight:
//     row i needs exactly floats [9i+5 .. 9i+8] = (coord_i, bond_i, ang_i,
//     tor_i) at FIXED offsets -> 4 scalar loads, no divergence, no per-elem
//     division (R4's demux paid both). Coalesced compact stores (f32/u16).
//     Memory-floor bound: 92 MB mandatory fetch ~= 15 us.
//  B) energy_kernel: 256 blocks x 1024 threads, one system per block/CU.
//     Compact coords (24 KB) fit L1 -> gathers L1-hot; conn u16 reads span
//     6-10 lines/wave (vs 64 on stride-9). Writes out[b] directly -> no
//     reduce kernel, no partials, 2 dispatches total.
// Evidence trail: R1/R2 latency-bound on stride-9 gathers; R3 8x staging
// duplication exploded FETCH to 310 MB; R4 sum-of-kernels ~60 us with
// demux issue-bound. The 92 MB line fetch is mandatory (every 64B line
// contains needed cols) -> compact once at full BW, compute from compact.

#define CBS 256   // compact block size
#define EBS 1024  // energy block size (16 waves -> one CU per system)

constexpr int BATCH  = 256;
constexpr int MAXLEN = 10000;
constexpr int NBT = 50, NAT = 100, NTT = 200;
constexpr float EPS = 1e-8f;

// d_ws layout (bytes); total ~16.9 MB
constexpr size_t OFF_CC = 0;                                  // [B][6000] f32 coords
constexpr size_t OFF_BC = OFF_CC + (size_t)BATCH * 6000 * 4;  // [B][6000] u16 bonds
constexpr size_t OFF_AC = OFF_BC + (size_t)BATCH * 6000 * 2;  // [B][8000] u16 angles
constexpr size_t OFF_TC = OFF_AC + (size_t)BATCH * 8000 * 2;  // [B][10000] u16 torsions

__global__ __launch_bounds__(CBS) void compact_kernel(
    const float* __restrict__ features,
    float* __restrict__ cc, unsigned short* __restrict__ bc,
    unsigned short* __restrict__ ac, unsigned short* __restrict__ tc)
{
    const unsigned gid = blockIdx.x * CBS + threadIdx.x;   // one thread per row
    const unsigned b   = gid / (unsigned)MAXLEN;
    const unsigned i   = gid - b * (unsigned)MAXLEN;
    if (b >= (unsigned)BATCH) return;

    const float* __restrict__ row = features + (size_t)b * MAXLEN * 9 + 9u * i + 5u;
    float vc = row[0];   // col 5: coord
    float vb = row[1];   // col 6: bond
    float va = row[2];   // col 7: angle
    float vt = row[3];   // col 8: torsion

    if (i < 6000u) cc[b * 6000u  + i] = vc;
    if (i < 5997u) bc[b * 6000u  + i] = (unsigned short)(int)vb;
    if (i < 7992u) ac[b * 8000u  + i] = (unsigned short)(int)va;
    if (i < 9985u) tc[b * 10000u + i] = (unsigned short)(int)vt;
}

__global__ __launch_bounds__(EBS) void energy_kernel(
    const float* __restrict__ cc,          // compact coords [B][6000]
    const unsigned short* __restrict__ bc, // [B][6000]
    const unsigned short* __restrict__ ac, // [B][8000]
    const unsigned short* __restrict__ tc, // [B][10000]
    const int*   __restrict__ lengths,
    const float* __restrict__ opt_pars,
    const float* __restrict__ bond_type,
    const float* __restrict__ angle_type,
    const float* __restrict__ tor_type,
    float*       __restrict__ out)         // [B]
{
    __shared__ float sbp[3 * NBT];
    __shared__ float sap[3 * NAT];
    __shared__ float stp[3 * NTT];
    __shared__ float sw[EBS / 64];

    const int b   = blockIdx.x;
    const int tid = threadIdx.x;

    for (int i = tid; i < NBT; i += EBS) {
        int idx = (int)bond_type[i];
        sbp[3*i+0] = opt_pars[3*idx+0];
        sbp[3*i+1] = opt_pars[3*idx+1];
        sbp[3*i+2] = opt_pars[3*idx+2];
    }
    for (int i = tid; i < NAT; i += EBS) {
        int idx = (int)angle_type[i];
        sap[3*i+0] = opt_pars[3*idx+0];
        sap[3*i+1] = opt_pars[3*idx+1];
        sap[3*i+2] = opt_pars[3*idx+2];
    }
    for (int i = tid; i < NTT; i += EBS) {
        int idx = (int)tor_type[i];
        stp[3*i+0] = opt_pars[3*idx+0];
        stp[3*i+1] = opt_pars[3*idx+1];
        stp[3*i+2] = opt_pars[3*idx+2];
    }
    __syncthreads();

    const float*          c  = cc + (size_t)b * 6000;
    const unsigned short* B_ = bc + (size_t)b * 6000;
    const unsigned short* A_ = ac + (size_t)b * 8000;
    const unsigned short* T_ = tc + (size_t)b * 10000;

    float acc = 0.0f;

    // ---- bonds: E = k * (r - r0)^2 ----
    {
        const int nb = lengths[b * 9 + 6] / 3;
        for (int t = tid; t < nb; t += EBS) {
            int i  = B_[3*t+0];
            int j  = B_[3*t+1];
            int ty = B_[3*t+2];
            float dx = c[3*i+0] - c[3*j+0];
            float dy = c[3*i+1] - c[3*j+1];
            float dz = c[3*i+2] - c[3*j+2];
            float r  = sqrtf(dx*dx + dy*dy + dz*dz + EPS);
            float k  = sbp[3*ty+0];
            float d  = r - sbp[3*ty+1];
            acc += k * d * d;
        }
    }

    // ---- angles: E = k * (theta - theta0)^2 ----
    {
        const int na = lengths[b * 9 + 7] / 4;
        for (int t = tid; t < na; t += EBS) {
            int i  = A_[4*t+0];
            int j  = A_[4*t+1];
            int k_ = A_[4*t+2];
            int ty = A_[4*t+3];
            float jx = c[3*j+0], jy = c[3*j+1], jz = c[3*j+2];
            float ux = c[3*i+0] - jx, uy = c[3*i+1] - jy, uz = c[3*i+2] - jz;
            float vx = c[3*k_+0] - jx, vy = c[3*k_+1] - jy, vz = c[3*k_+2] - jz;
            float uv = ux*vx + uy*vy + uz*vz;
            float uu = ux*ux + uy*uy + uz*uz;
            float vv = vx*vx + vy*vy + vz*vz;
            float cth = uv * rsqrtf((uu + EPS) * (vv + EPS));
            cth = fminf(fmaxf(cth, -1.0f + 1e-6f), 1.0f - 1e-6f);
            float theta = acosf(cth);
            float k  = sap[3*ty+0];
            float d  = theta - sap[3*ty+1];
            acc += k * d * d;
        }
    }

    // ---- torsions: E = k * (1 + cos(n*phi - phi0)) ----
    {
        const int nt = lengths[b * 9 + 8] / 5;
        for (int t = tid; t < nt; t += EBS) {
            int i  = T_[5*t+0];
            int j  = T_[5*t+1];
            int k_ = T_[5*t+2];
            int l  = T_[5*t+3];
            int ty = T_[5*t+4];
            float ix = c[3*i+0],  iy = c[3*i+1],  iz = c[3*i+2];
            float jx = c[3*j+0],  jy = c[3*j+1],  jz = c[3*j+2];
            float kx = c[3*k_+0], ky = c[3*k_+1], kz = c[3*k_+2];
            float lx = c[3*l+0],  ly = c[3*l+1],  lz = c[3*l+2];
            float b1x = jx - ix, b1y = jy - iy, b1z = jz - iz;
            float b2x = kx - jx, b2y = ky - jy, b2z = kz - jz;
            float b3x = lx - kx, b3y = ly - ky, b3z = lz - kz;
            float n1x = b1y*b2z - b1z*b2y;
            float n1y = b1z*b2x - b1x*b2z;
            float n1z = b1x*b2y - b1y*b2x;
            float n2x = b2y*b3z - b2z*b3y;
            float n2y = b2z*b3x - b2x*b3z;
            float n2z = b2x*b3y - b2y*b3x;
            float inv = rsqrtf(b2x*b2x + b2y*b2y + b2z*b2z + EPS);
            float hx = b2x * inv, hy = b2y * inv, hz = b2z * inv;
            float m1x = n1y*hz - n1z*hy;
            float m1y = n1z*hx - n1x*hz;
            float m1z = n1x*hy - n1y*hx;
            float sy = m1x*n2x + m1y*n2y + m1z*n2z;
            float sx = n1x*n2x + n1y*n2y + n1z*n2z;
            float phi = atan2f(sy, sx);
            float k  = stp[3*ty+0];
            float p0 = stp[3*ty+1];
            float n  = stp[3*ty+2];
            acc += k * (1.0f + cosf(n * phi - p0));
        }
    }

    for (int off = 32; off > 0; off >>= 1)
        acc += __shfl_down(acc, off, 64);
    const int wave = tid >> 6, lane = tid & 63;
    if (lane == 0) sw[wave] = acc;
    __syncthreads();
    if (tid == 0) {
        float v = 0.0f;
        #pragma unroll
        for (int w = 0; w < EBS / 64; ++w) v += sw[w];
        out[b] = v;
    }
}

extern "C" void kernel_launch(void* const* d_in, const int* in_sizes, int n_in,
                              void* d_out, int out_size, void* d_ws, size_t ws_size,
                              hipStream_t stream) {
    const float* features   = (const float*)d_in[0];
    const int*   lengths    = (const int*)  d_in[1];
    const float* opt_pars   = (const float*)d_in[2];
    const float* bond_type  = (const float*)d_in[3];
    const float* angle_type = (const float*)d_in[4];
    const float* tor_type   = (const float*)d_in[5];
    float* out = (float*)d_out;
    char*  ws  = (char*)d_ws;

    float*          cc = (float*)(ws + OFF_CC);
    unsigned short* bc = (unsigned short*)(ws + OFF_BC);
    unsigned short* ac = (unsigned short*)(ws + OFF_AC);
    unsigned short* tc = (unsigned short*)(ws + OFF_TC);

    const int B = out_size;  // 256
    const int rows = BATCH * MAXLEN;                       // 2.56M threads
    compact_kernel<<<(rows + CBS - 1) / CBS, CBS, 0, stream>>>(
        features, cc, bc, ac, tc);
    energy_kernel<<<B, EBS, 0, stream>>>(
        cc, bc, ac, tc, lengths, opt_pars, bond_type, angle_type, tor_type, out);
}

// Round 6
// 148.675 us; speedup vs baseline: 1.3632x; 1.0321x over previous
//
#include <hip/hip_runtime.h>

// LocalEnergyOpt R6: fully fused, one kernel, one block per system (grid 256
// = 1 block/CU, 1024 threads = 16 waves).
// Staging: R5's structural trick — row i needs exactly floats [9i+5..9i+8]
// (coord_i, bond_i, angle_i, torsion_i) at FIXED offsets -> one dwordx4 per
// row, zero demux arithmetic, every 64B line of the system's 360 KB touched
// exactly once -> 92 MB mandatory fetch at full BW (~15 us). Demux lands
// directly in LDS (coords f32 24KB + conn u16 48KB + params 4.2KB = 76 KB),
// killing R5's 17MB ws write + 17MB re-read + second dispatch + phase-B
// global gathers. Compute phase is pure LDS + VALU (~7 us).
// Evidence: R1-R3 latency-bound on stride-9 gathers; R4/R5 two-phase
// Sigma-kernels ~48us with ~6us round-trip + serialization overhead.

#define EBS 1024

constexpr int BATCH  = 256;
constexpr int MAXLEN = 10000;
constexpr int NBT = 50, NAT = 100, NTT = 200;
constexpr float EPS = 1e-8f;

// LDS layout (bytes)
constexpr int OFF_SC  = 0;                    // 6000 f32 coords
constexpr int OFF_SBP = OFF_SC  + 6000 * 4;   // 150 f32 bond params
constexpr int OFF_SAP = OFF_SBP + 150 * 4;    // 300 f32 angle params
constexpr int OFF_STP = OFF_SAP + 300 * 4;    // 600 f32 torsion params
constexpr int OFF_SW  = OFF_STP + 600 * 4;    // 16 f32 wave partials
constexpr int OFF_SB  = OFF_SW  + 16 * 4;     // 6000 u16 bond raw
constexpr int OFF_SA  = OFF_SB  + 6000 * 2;   // 8000 u16 angle raw
constexpr int OFF_ST  = OFF_SA  + 8000 * 2;   // 10000 u16 torsion raw
constexpr int SMEM_BYTES = OFF_ST + 10000 * 2;  // 76264 B

__global__ __launch_bounds__(EBS) void energy_kernel(
    const float* __restrict__ features,   // [B, 10000, 9]
    const int*   __restrict__ lengths,    // [B, 9]
    const float* __restrict__ opt_pars,   // [350, 3]
    const float* __restrict__ bond_type,  // [50]
    const float* __restrict__ angle_type, // [100]
    const float* __restrict__ tor_type,   // [200]
    float*       __restrict__ out)        // [B]
{
    extern __shared__ char smem[];
    float*          sc  = (float*)(smem + OFF_SC);
    float*          sbp = (float*)(smem + OFF_SBP);
    float*          sap = (float*)(smem + OFF_SAP);
    float*          stp = (float*)(smem + OFF_STP);
    float*          sw  = (float*)(smem + OFF_SW);
    unsigned short* sb  = (unsigned short*)(smem + OFF_SB);
    unsigned short* sa  = (unsigned short*)(smem + OFF_SA);
    unsigned short* st  = (unsigned short*)(smem + OFF_ST);

    const int b   = blockIdx.x;
    const int tid = threadIdx.x;
    const float* __restrict__ fb = features + (size_t)b * MAXLEN * 9;

    // ---- resolved param tables (tiny, L2-hot) ----
    for (int i = tid; i < NBT; i += EBS) {
        int idx = (int)bond_type[i];
        sbp[3*i+0] = opt_pars[3*idx+0];
        sbp[3*i+1] = opt_pars[3*idx+1];
        sbp[3*i+2] = opt_pars[3*idx+2];
    }
    for (int i = tid; i < NAT; i += EBS) {
        int idx = (int)angle_type[i];
        sap[3*i+0] = opt_pars[3*idx+0];
        sap[3*i+1] = opt_pars[3*idx+1];
        sap[3*i+2] = opt_pars[3*idx+2];
    }
    for (int i = tid; i < NTT; i += EBS) {
        int idx = (int)tor_type[i];
        stp[3*i+0] = opt_pars[3*idx+0];
        stp[3*i+1] = opt_pars[3*idx+1];
        stp[3*i+2] = opt_pars[3*idx+2];
    }

    // ---- single streaming pass: row i -> dwordx4 at 9i+5, demux to LDS ----
    #pragma unroll 2
    for (int i = tid; i < MAXLEN; i += EBS) {
        const float* __restrict__ row = fb + 9 * i + 5;
        float vc = row[0];   // col 5: coord
        float vb = row[1];   // col 6: bond
        float va = row[2];   // col 7: angle
        float vt = row[3];   // col 8: torsion
        if (i < 6000)  sc[i] = vc;
        if (i < 6000)  sb[i] = (unsigned short)(int)vb;
        if (i < 8000)  sa[i] = (unsigned short)(int)va;
        st[i] = (unsigned short)(int)vt;   // i < 10000 always
    }
    __syncthreads();

    float acc = 0.0f;

    // ---- bonds: E = k * (r - r0)^2 ----
    {
        const int nb = lengths[b * 9 + 6] / 3;
        for (int t = tid; t < nb; t += EBS) {
            int i  = sb[3*t+0];
            int j  = sb[3*t+1];
            int ty = sb[3*t+2];
            float dx = sc[3*i+0] - sc[3*j+0];
            float dy = sc[3*i+1] - sc[3*j+1];
            float dz = sc[3*i+2] - sc[3*j+2];
            float r  = sqrtf(dx*dx + dy*dy + dz*dz + EPS);
            float k  = sbp[3*ty+0];
            float d  = r - sbp[3*ty+1];
            acc += k * d * d;
        }
    }

    // ---- angles: E = k * (theta - theta0)^2 ----
    {
        const int na = lengths[b * 9 + 7] / 4;
        for (int t = tid; t < na; t += EBS) {
            int i  = sa[4*t+0];
            int j  = sa[4*t+1];
            int k_ = sa[4*t+2];
            int ty = sa[4*t+3];
            float jx = sc[3*j+0], jy = sc[3*j+1], jz = sc[3*j+2];
            float ux = sc[3*i+0] - jx, uy = sc[3*i+1] - jy, uz = sc[3*i+2] - jz;
            float vx = sc[3*k_+0] - jx, vy = sc[3*k_+1] - jy, vz = sc[3*k_+2] - jz;
            float uv = ux*vx + uy*vy + uz*vz;
            float uu = ux*ux + uy*uy + uz*uz;
            float vv = vx*vx + vy*vy + vz*vz;
            float cth = uv * rsqrtf((uu + EPS) * (vv + EPS));
            cth = fminf(fmaxf(cth, -1.0f + 1e-6f), 1.0f - 1e-6f);
            float theta = acosf(cth);
            float k  = sap[3*ty+0];
            float d  = theta - sap[3*ty+1];
            acc += k * d * d;
        }
    }

    // ---- torsions: E = k * (1 + cos(n*phi - phi0)) ----
    {
        const int nt = lengths[b * 9 + 8] / 5;
        for (int t = tid; t < nt; t += EBS) {
            int i  = st[5*t+0];
            int j  = st[5*t+1];
            int k_ = st[5*t+2];
            int l  = st[5*t+3];
            int ty = st[5*t+4];
            float ix = sc[3*i+0],  iy = sc[3*i+1],  iz = sc[3*i+2];
            float jx = sc[3*j+0],  jy = sc[3*j+1],  jz = sc[3*j+2];
            float kx = sc[3*k_+0], ky = sc[3*k_+1], kz = sc[3*k_+2];
            float lx = sc[3*l+0],  ly = sc[3*l+1],  lz = sc[3*l+2];
            float b1x = jx - ix, b1y = jy - iy, b1z = jz - iz;
            float b2x = kx - jx, b2y = ky - jy, b2z = kz - jz;
            float b3x = lx - kx, b3y = ly - ky, b3z = lz - kz;
            float n1x = b1y*b2z - b1z*b2y;
            float n1y = b1z*b2x - b1x*b2z;
            float n1z = b1x*b2y - b1y*b2x;
            float n2x = b2y*b3z - b2z*b3y;
            float n2y = b2z*b3x - b2x*b3z;
            float n2z = b2x*b3y - b2y*b3x;
            float inv = rsqrtf(b2x*b2x + b2y*b2y + b2z*b2z + EPS);
            float hx = b2x * inv, hy = b2y * inv, hz = b2z * inv;
            float m1x = n1y*hz - n1z*hy;
            float m1y = n1z*hx - n1x*hz;
            float m1z = n1x*hy - n1y*hx;
            float sy = m1x*n2x + m1y*n2y + m1z*n2z;
            float sx = n1x*n2x + n1y*n2y + n1z*n2z;
            float phi = atan2f(sy, sx);
            float k  = stp[3*ty+0];
            float p0 = stp[3*ty+1];
            float n  = stp[3*ty+2];
            acc += k * (1.0f + cosf(n * phi - p0));
        }
    }

    // ---- reduce: 64-lane shuffle, then cross-wave via LDS ----
    for (int off = 32; off > 0; off >>= 1)
        acc += __shfl_down(acc, off, 64);
    const int wave = tid >> 6, lane = tid & 63;
    if (lane == 0) sw[wave] = acc;
    __syncthreads();
    if (tid == 0) {
        float v = 0.0f;
        #pragma unroll
        for (int w = 0; w < EBS / 64; ++w) v += sw[w];
        out[b] = v;
    }
}

extern "C" void kernel_launch(void* const* d_in, const int* in_sizes, int n_in,
                              void* d_out, int out_size, void* d_ws, size_t ws_size,
                              hipStream_t stream) {
    const float* features   = (const float*)d_in[0];
    const int*   lengths    = (const int*)  d_in[1];
    const float* opt_pars   = (const float*)d_in[2];
    const float* bond_type  = (const float*)d_in[3];
    const float* angle_type = (const float*)d_in[4];
    const float* tor_type   = (const float*)d_in[5];
    float* out = (float*)d_out;

    // 76 KB dynamic LDS (> 64 KB default); idempotent, capture-safe.
    hipFuncSetAttribute((const void*)energy_kernel,
                        hipFuncAttributeMaxDynamicSharedMemorySize, SMEM_BYTES);

    const int B = out_size;  // 256
    energy_kernel<<<B, EBS, SMEM_BYTES, stream>>>(
        features, lengths, opt_pars, bond_type, angle_type, tor_type, out);
}